// Round 10
// baseline (607.624 us; speedup 1.0000x reference)
//
#include <hip/hip_runtime.h>
#include <math.h>

typedef __attribute__((ext_vector_type(8))) _Float16 half8;
typedef __attribute__((ext_vector_type(4))) _Float16 half4;
typedef __attribute__((ext_vector_type(4))) float    floatx4;

#define N_NODES 10000
#define M_PAD   10112      // 79 * 128
#define MTILES  79
#define E_EDGES 160000
#define DIM     256
#define R_REL   237
#define L_LAYERS 6
#define B_BATCH 128
#define K_BATCH 33
#define K13     3328       // 13*256
#define KSPLIT  4
#define KSLICE  832        // K13/KSPLIT (halves)
#define KS_STEPS 26        // KSLICE/32
#define EPS_STD 1e-6f
#define EPS_LN  1e-5f

// async global->LDS, 16B per lane; LDS dest = wave-uniform base + lane*16
__device__ __forceinline__ void gload16(const void* g, void* lds) {
    __builtin_amdgcn_global_load_lds(
        (const __attribute__((address_space(1))) unsigned int*)g,
        (__attribute__((address_space(3))) unsigned int*)lds, 16, 0, 0);
}

// ---------------- CSR build ----------------
__global__ void hist_kernel(const int* __restrict__ dst, int* __restrict__ deg) {
    int e = blockIdx.x * blockDim.x + threadIdx.x;
    if (e < E_EDGES) atomicAdd(&deg[dst[e]], 1);
}

__global__ void scan_kernel(const int* __restrict__ deg_in, int* __restrict__ offs,
                            int* __restrict__ cursor, float* __restrict__ sum_log) {
    __shared__ int   part[1024];
    __shared__ float slog[1024];
    int t = threadIdx.x;
    const int CH = 10;
    int base = t * CH;
    int lsum = 0; float ls = 0.f;
    for (int j = 0; j < CH; j++) {
        int i = base + j;
        if (i < N_NODES) { int d = deg_in[i]; lsum += d; ls += logf((float)(d + 1)); }
    }
    part[t] = lsum; slog[t] = ls;
    __syncthreads();
    for (int off = 1; off < 1024; off <<= 1) {
        int v = (t >= off) ? part[t - off] : 0;
        __syncthreads();
        part[t] += v;
        __syncthreads();
    }
    int run = part[t] - lsum;
    for (int j = 0; j < CH; j++) {
        int i = base + j;
        if (i < N_NODES) { offs[i] = run; cursor[i] = run; run += deg_in[i]; }
    }
    __syncthreads();
    for (int off = 512; off > 0; off >>= 1) {
        if (t < off) slog[t] += slog[t + off];
        __syncthreads();
    }
    if (t == 0) sum_log[0] = slog[0];
}

__global__ void fill_kernel(const int* __restrict__ src, const int* __restrict__ dst,
                            const int* __restrict__ et, int* __restrict__ cursor,
                            int* __restrict__ csr_src, int* __restrict__ csr_et) {
    int e = blockIdx.x * blockDim.x + threadIdx.x;
    if (e < E_EDGES) {
        int d = dst[e];
        int p = atomicAdd(&cursor[d], 1);
        csr_src[p] = src[e];
        csr_et[p]  = et[e];
    }
}

__global__ void scales_kernel(const int* __restrict__ deg_in, const float* __restrict__ sum_log,
                              float* __restrict__ s1, float* __restrict__ s2) {
    int i = blockIdx.x * blockDim.x + threadIdx.x;
    if (i < N_NODES) {
        float mean = sum_log[0] * (1.0f / (float)N_NODES);
        float sc = logf((float)(deg_in[i] + 1)) / mean;
        s1[i] = sc;
        s2[i] = 1.0f / fmaxf(sc, 0.01f);
    }
}

// -------- W permute+transpose to fp16: Wt[l][n][k'] = W[l][korig(k')][n] --------
// new A col order: k' = t*768 + s*256 + d, x at 3072+; korig = (t*256+d)*3 + s
__global__ void wt_kernel(const float* __restrict__ Ws, _Float16* __restrict__ Wt) {
    int idx = blockIdx.x * 256 + threadIdx.x;
    const int TOT = L_LAYERS * 256 * K13;
    if (idx >= TOT) return;
    int l = idx / (256 * K13);
    int r = idx - l * (256 * K13);
    int n = r / K13, k = r - n * K13;
    int korig;
    if (k < 3072) {
        int t = k / 768;
        int rem = k - t * 768;
        int s = rem >> 8;
        int d = rem & 255;
        korig = (t * 256 + d) * 3 + s;
    } else {
        korig = k;
    }
    Wt[idx] = (_Float16)Ws[(size_t)l * K13 * 256 + (size_t)korig * 256 + n];
}

// -------- fp32 -> fp16 converter --------
__global__ void cvt_kernel(const float* __restrict__ in, _Float16* __restrict__ outp, int n) {
    int i = blockIdx.x * 256 + threadIdx.x;
    if (i < n) outp[i] = (_Float16)in[i];
}

// ---- aggregation: one wave per node, 2 edges/iteration (lane halves), fp16 gather ----
__global__ void agg_kernel(const float* __restrict__ x, const _Float16* __restrict__ xh,
                           const _Float16* __restrict__ relh,
                           const int* __restrict__ offs, const int* __restrict__ deg_in,
                           const int* __restrict__ csr_src, const int* __restrict__ csr_et,
                           _Float16* __restrict__ feats) {
    int wid  = threadIdx.x >> 6;
    int lane = threadIdx.x & 63;
    int node = blockIdx.x * 4 + wid;
    if (node >= N_NODES) return;
    int half = lane >> 5;
    int sub  = lane & 31;
    int off = offs[node];
    int end = off + deg_in[node];
    const half8* xh8 = (const half8*)xh;
    const half8* rh8 = (const half8*)relh;

    float s_[8], q_[8], mx_[8], mn_[8];
    #pragma unroll
    for (int i = 0; i < 8; i++) { s_[i] = 0.f; q_[i] = 0.f; mx_[i] = -INFINITY; mn_[i] = INFINITY; }

    for (int base = off; base < end; base += 2) {
        int e = base + half;
        if (e < end) {
            int sN = csr_src[e];
            int et = csr_et[e];
            half8 xv = xh8[(size_t)sN * 32 + sub];
            half8 rv = rh8[(size_t)et * 32 + sub];
            #pragma unroll
            for (int i = 0; i < 8; i++) {
                float m = (float)xv[i] * (float)rv[i];
                s_[i] += m; q_[i] += m * m;
                mx_[i] = fmaxf(mx_[i], m);
                mn_[i] = fminf(mn_[i], m);
            }
        }
    }
    #pragma unroll
    for (int i = 0; i < 8; i++) {
        s_[i] += __shfl_xor(s_[i], 32);
        q_[i] += __shfl_xor(q_[i], 32);
        mx_[i] = fmaxf(mx_[i], __shfl_xor(mx_[i], 32));
        mn_[i] = fminf(mn_[i], __shfl_xor(mn_[i], 32));
    }
    const float4* xrow = (const float4*)(x + (size_t)node * 256);
    float4 xa = xrow[sub * 2], xb = xrow[sub * 2 + 1];
    float xs[8] = {xa.x, xa.y, xa.z, xa.w, xb.x, xb.y, xb.z, xb.w};
    #pragma unroll
    for (int i = 0; i < 8; i++) {
        s_[i] += xs[i]; q_[i] += xs[i] * xs[i];
        mx_[i] = fmaxf(mx_[i], xs[i]);
        mn_[i] = fminf(mn_[i], xs[i]);
    }
    float inv = 1.0f / (float)(end - off + 1);
    half8 hm, hx, hn, hs;
    #pragma unroll
    for (int i = 0; i < 8; i++) {
        float mean = s_[i] * inv;
        float sd = sqrtf(fmaxf(q_[i] * inv - mean * mean, EPS_STD));
        hm[i] = (_Float16)mean; hx[i] = (_Float16)mx_[i];
        hn[i] = (_Float16)mn_[i]; hs[i] = (_Float16)sd;
    }
    half8* fout = (half8*)(feats + (size_t)node * 1024);
    if (half == 0) {
        fout[0 * 32 + sub] = hm;
        fout[1 * 32 + sub] = hx;
    } else {
        fout[2 * 32 + sub] = hn;
        fout[3 * 32 + sub] = hs;
    }
}

// ---------------- fp16 MFMA GEMM: 128x128 tiles, 2x2 waves (64x64 each) ----------------
// A: DIRECT global->VGPR in fragment layout, scale folded in-register (no LDS round trip).
// B: global_load_lds into 3 x 8KB buffers, counted vmcnt(6). grid = 632 = 8*79 XCD-exact.
__launch_bounds__(256, 3)
__global__ void gemm_kernel(const _Float16* __restrict__ feats, const _Float16* __restrict__ xh,
                            const _Float16* __restrict__ Wt, const float* __restrict__ s1a,
                            const float* __restrict__ s2a, _Float16* __restrict__ hbuf) {
    __shared__ _Float16 sB[3][128 * 32];   // 24 KB total

    // XCD swizzle: 632 = 8*79; each XCD owns one (ks,nh) pair -> B slice L2-resident
    int xcd = blockIdx.x & 7, loc = blockIdx.x >> 3;
    int lin = xcd * MTILES + loc;
    int ks  = lin / (2 * MTILES);
    int rem = lin - ks * (2 * MTILES);
    int nh  = rem / MTILES;
    int m   = rem - nh * MTILES;
    const int i0    = m * 128;
    const int n0    = nh * 128;
    const int kbase = ks * KSLICE;

    const int tid   = threadIdx.x;
    const int lane  = tid & 63;
    const int w     = tid >> 6;
    const int wr    = w >> 1;               // wave row 0..1
    const int wc    = w & 1;                // wave col 0..1
    const int row_l = lane & 15;
    const int kq    = lane >> 4;

    // B reader LDS offsets (halves), XOR chunk swizzle: chunk' = chunk ^ ((row>>1)&3)
    int b_off[4];
    #pragma unroll
    for (int cf = 0; cf < 4; cf++) {
        int n_ = wc * 64 + cf * 16 + row_l;
        b_off[cf] = n_ * 32 + ((kq ^ ((n_ >> 1) & 3)) & 3) * 8;
    }

    // ---- A: per-lane fragment bases + per-rf scales (row = i0 + wr*64 + rf*16 + row_l) ----
    const int arow0 = i0 + wr * 64 + row_l;
    const _Float16* pfeat = feats + (size_t)arow0 * 1024 + kq * 8;
    const _Float16* pxh   = xh    + (size_t)arow0 * 256  + kq * 8;
    float s1r[4], s2r[4];
    #pragma unroll
    for (int rf = 0; rf < 4; rf++) {
        s1r[rf] = s1a[arow0 + rf * 16];
        s2r[rf] = s2a[arow0 + rf * 16];
    }

    // ---- B staging: 128 rows, 2 gload16 per wave; pre-swizzled source, linear dest ----
    const char* b_src[2];
    #pragma unroll
    for (int j = 0; j < 2; j++) {
        int rloc = j * 64 + w * 16 + (lane >> 2);
        int c = (lane & 3) ^ ((rloc >> 1) & 3);
        b_src[j] = (const char*)(Wt + (size_t)(n0 + rloc) * K13 + kbase + c * 8);
    }

    floatx4 acc[4][4];
    #pragma unroll
    for (int rf = 0; rf < 4; rf++)
        #pragma unroll
        for (int cf = 0; cf < 4; cf++)
            acc[rf][cf] = (floatx4){0.f, 0.f, 0.f, 0.f};

    half8 a0[4], a1[4], a2[4];

// direct A fragment load for stage S into AR[0..3] (4 global 16B loads)
#define ALOADD(S, AR) do {                                                    \
    int k0_ = kbase + (S) * 32;                                               \
    const _Float16* p_; int rs_;                                              \
    if (k0_ < 3072) {                                                         \
        int t_ = k0_ / 768;                                                   \
        int rem_ = k0_ - t_ * 768;                                            \
        p_ = pfeat + t_ * 256 + (rem_ & 255);                                 \
        rs_ = 16 * 1024;                                                      \
    } else {                                                                  \
        p_ = pxh + (k0_ - 3072);                                              \
        rs_ = 16 * 256;                                                       \
    }                                                                         \
    AR[0] = *(const half8*)(p_);                                              \
    AR[1] = *(const half8*)(p_ + rs_);                                        \
    AR[2] = *(const half8*)(p_ + 2 * rs_);                                    \
    AR[3] = *(const half8*)(p_ + 3 * rs_);                                    \
} while (0)

#define BSTAGE(BUF, S) do {                                                   \
    size_t koff_ = (size_t)(S) * 64;                                          \
    gload16(b_src[0] + koff_, (char*)(&sB[BUF][0]) + (0 * 64 + w * 16) * 64); \
    gload16(b_src[1] + koff_, (char*)(&sB[BUF][0]) + (1 * 64 + w * 16) * 64); \
} while (0)

// compute step S from B buffer CB and A regs AR (scale applied in-register)
#define COMPUTE(CB, S, AR) do {                                               \
    int k0_ = kbase + (S) * 32;                                               \
    int sI_ = 0;                                                              \
    if (k0_ < 3072) { int rem_ = k0_ - (k0_ / 768) * 768; sI_ = rem_ >> 8; }  \
    half8 bf[4], af[4];                                                       \
    _Pragma("unroll")                                                         \
    for (int cf = 0; cf < 4; cf++) bf[cf] = *(const half8*)(&sB[CB][b_off[cf]]); \
    _Pragma("unroll")                                                         \
    for (int rf = 0; rf < 4; rf++) {                                          \
        float sc_ = (sI_ == 0) ? 1.0f : ((sI_ == 1) ? s1r[rf] : s2r[rf]);     \
        af[rf] = AR[rf] * (_Float16)sc_;                                      \
    }                                                                         \
    __builtin_amdgcn_s_setprio(1);                                            \
    _Pragma("unroll")                                                         \
    for (int rf = 0; rf < 4; rf++)                                            \
        _Pragma("unroll")                                                     \
        for (int cf = 0; cf < 4; cf++)                                        \
            acc[rf][cf] = __builtin_amdgcn_mfma_f32_16x16x32_f16(af[rf], bf[cf], acc[rf][cf], 0, 0, 0); \
    __builtin_amdgcn_s_setprio(0);                                            \
} while (0)

// one step: stage S ready (6 newest ops = stage S+1 may remain), barrier for B,
// issue stage S+2 (4 A-reg + 2 B-lds), compute
#define STEP(S, CUR, ACUR, NXT, ANXT) do {                                    \
    asm volatile("s_waitcnt vmcnt(6)" ::: "memory");                          \
    __builtin_amdgcn_s_barrier();                                             \
    ALOADD((S) + 2, ANXT);                                                    \
    BSTAGE(NXT, (S) + 2);                                                     \
    COMPUTE(CUR, S, ACUR);                                                    \
} while (0)

    // prologue: stages 0,1 in flight (6 vm-ops each per wave: 4 A-reg + 2 B-lds)
    ALOADD(0, a0); BSTAGE(0, 0);
    ALOADD(1, a1); BSTAGE(1, 1);

    // steps 0..23 (8 triple-iterations; prefetch reaches stage 25 exactly)
    int s = 0;
    for (int it = 0; it < 8; ++it, s += 3) {
        STEP(s + 0, 0, a0, 2, a2);
        STEP(s + 1, 1, a1, 0, a0);
        STEP(s + 2, 2, a2, 1, a1);
    }
    // step 24 (buf0): stage 25's 6 ops may remain in flight
    asm volatile("s_waitcnt vmcnt(6)" ::: "memory");
    __builtin_amdgcn_s_barrier();
    COMPUTE(0, 24, a0);
    // step 25 (buf1): drain all
    asm volatile("s_waitcnt vmcnt(0)" ::: "memory");
    __builtin_amdgcn_s_barrier();
    COMPUTE(1, 25, a1);

#undef ALOADD
#undef BSTAGE
#undef COMPUTE
#undef STEP

    // C/D layout: col = lane&15, row = (lane>>4)*4 + j ; wave tile (wr*64, wc*64)
    _Float16* outb = hbuf + (size_t)ks * M_PAD * 256;
    #pragma unroll
    for (int rf = 0; rf < 4; rf++) {
        #pragma unroll
        for (int j = 0; j < 4; j++) {
            int grow = i0 + wr * 64 + rf * 16 + kq * 4 + j;
            _Float16* orow = outb + (size_t)grow * 256 + n0 + wc * 64;
            #pragma unroll
            for (int cf = 0; cf < 4; cf++)
                orow[cf * 16 + row_l] = (_Float16)acc[rf][cf][j];
        }
    }
}

// ---------------- 4-way reduce + bias + LN + relu + residual (+fp16 mirror) ----------------
__global__ void ln_kernel(const _Float16* __restrict__ hbuf, const float* __restrict__ xin,
                          const float* __restrict__ bvec, const float* __restrict__ gvec,
                          const float* __restrict__ evec, float* __restrict__ xout,
                          _Float16* __restrict__ xhout) {
    int wid = threadIdx.x >> 6, lane = threadIdx.x & 63;
    int row = blockIdx.x * 4 + wid;
    if (row >= N_NODES) return;
    const half4* p0 = (const half4*)(hbuf + (size_t)row * 256);
    const half4* p1 = (const half4*)(hbuf + (size_t)M_PAD * 256     + (size_t)row * 256);
    const half4* p2 = (const half4*)(hbuf + (size_t)M_PAD * 256 * 2 + (size_t)row * 256);
    const half4* p3 = (const half4*)(hbuf + (size_t)M_PAD * 256 * 3 + (size_t)row * 256);
    half4 h0 = p0[lane], h1 = p1[lane], h2 = p2[lane], h3 = p3[lane];
    float4 bv = ((const float4*)bvec)[lane];
    float4 hv;
    hv.x = (float)h0.x + (float)h1.x + (float)h2.x + (float)h3.x + bv.x;
    hv.y = (float)h0.y + (float)h1.y + (float)h2.y + (float)h3.y + bv.y;
    hv.z = (float)h0.z + (float)h1.z + (float)h2.z + (float)h3.z + bv.z;
    hv.w = (float)h0.w + (float)h1.w + (float)h2.w + (float)h3.w + bv.w;
    float s = hv.x + hv.y + hv.z + hv.w;
    float qsq = hv.x*hv.x + hv.y*hv.y + hv.z*hv.z + hv.w*hv.w;
    #pragma unroll
    for (int off = 1; off < 64; off <<= 1) {
        s   += __shfl_xor(s, off);
        qsq += __shfl_xor(qsq, off);
    }
    float mu  = s * (1.0f / 256.0f);
    float var = qsq * (1.0f / 256.0f) - mu * mu;
    float rs  = rsqrtf(var + EPS_LN);
    float4 g = ((const float4*)gvec)[lane];
    float4 e = ((const float4*)evec)[lane];
    float4 xv = ((const float4*)(xin + (size_t)row * 256))[lane];
    float4 o;
    o.x = fmaxf((hv.x - mu) * rs * g.x + e.x, 0.f) + xv.x;
    o.y = fmaxf((hv.y - mu) * rs * g.y + e.y, 0.f) + xv.y;
    o.z = fmaxf((hv.z - mu) * rs * g.z + e.z, 0.f) + xv.z;
    o.w = fmaxf((hv.w - mu) * rs * g.w + e.w, 0.f) + xv.w;
    ((float4*)(xout + (size_t)row * 256))[lane] = o;
    half4 oh = { (_Float16)o.x, (_Float16)o.y, (_Float16)o.z, (_Float16)o.w };
    ((half4*)(xhout + (size_t)row * 256))[lane] = oh;
}

// ---------------- final scoring ----------------
__global__ void score_kernel(const float* __restrict__ x, const float* __restrict__ remb,
                             const int* __restrict__ batch, float* __restrict__ out) {
    int wid = threadIdx.x >> 6, lane = threadIdx.x & 63;
    int g = blockIdx.x * 4 + wid;
    if (g >= B_BATCH * K_BATCH) return;
    int si = batch[g * 3 + 0], ri = batch[g * 3 + 1], ti = batch[g * 3 + 2];
    const float4* xs = (const float4*)(x + (size_t)si * 256);
    const float4* xr = (const float4*)(remb + (size_t)ri * 256);
    const float4* xt = (const float4*)(x + (size_t)ti * 256);
    float4 a = xs[lane], r = xr[lane], t = xt[lane];
    float p = a.x*r.x*t.x + a.y*r.y*t.y + a.z*r.z*t.z + a.w*r.w*t.w;
    #pragma unroll
    for (int off = 1; off < 64; off <<= 1) p += __shfl_xor(p, off);
    if (lane == 0) out[g] = p;
}

extern "C" void kernel_launch(void* const* d_in, const int* in_sizes, int n_in,
                              void* d_out, int out_size, void* d_ws, size_t ws_size,
                              hipStream_t stream) {
    const float* x_in     = (const float*)d_in[0];
    const float* rel_embs = (const float*)d_in[1];
    const float* Ws       = (const float*)d_in[2];
    const float* bs       = (const float*)d_in[3];
    const float* ln_s     = (const float*)d_in[4];
    const float* ln_b     = (const float*)d_in[5];
    const float* remb     = (const float*)d_in[6];
    const int*   eidx     = (const int*)d_in[7];
    const int*   etype    = (const int*)d_in[8];
    const int*   batch    = (const int*)d_in[9];
    float* out = (float*)d_out;

    char* wp = (char*)d_ws;
    size_t o = 0;
    auto alloc = [&](size_t bytes) { void* p = wp + o; o += (bytes + 255) & ~255ull; return p; };
    int*      deg_in  = (int*)     alloc((size_t)N_NODES * 4);
    int*      offs    = (int*)     alloc((size_t)N_NODES * 4);
    int*      cursor  = (int*)     alloc((size_t)N_NODES * 4);
    float*    s1      = (float*)   alloc((size_t)M_PAD * 4);
    float*    s2      = (float*)   alloc((size_t)M_PAD * 4);
    float*    sum_log = (float*)   alloc(256);
    int*      csr_src = (int*)     alloc((size_t)E_EDGES * 4);
    int*      csr_et  = (int*)     alloc((size_t)E_EDGES * 4);
    _Float16* feats   = (_Float16*)alloc((size_t)M_PAD * 1024 * 2);           // 20.7 MB
    _Float16* Wt      = (_Float16*)alloc((size_t)L_LAYERS * 256 * K13 * 2);   // 10.2 MB
    _Float16* hbuf    = (_Float16*)alloc((size_t)KSPLIT * M_PAD * 256 * 2);   // 20.7 MB
    float*    xb0     = (float*)   alloc((size_t)M_PAD * 256 * 4);
    float*    xb1     = (float*)   alloc((size_t)M_PAD * 256 * 4);
    _Float16* xh0     = (_Float16*)alloc((size_t)M_PAD * 256 * 2);
    _Float16* xh1     = (_Float16*)alloc((size_t)M_PAD * 256 * 2);
    _Float16* relh    = (_Float16*)alloc((size_t)L_LAYERS * R_REL * 256 * 2); // 0.73 MB

    const int* src  = eidx;
    const int* dstp = eidx + E_EDGES;

    hipMemsetAsync(deg_in, 0, (size_t)N_NODES * 4, stream);
    hist_kernel<<<(E_EDGES + 255) / 256, 256, 0, stream>>>(dstp, deg_in);
    scan_kernel<<<1, 1024, 0, stream>>>(deg_in, offs, cursor, sum_log);
    fill_kernel<<<(E_EDGES + 255) / 256, 256, 0, stream>>>(src, dstp, etype, cursor, csr_src, csr_et);
    scales_kernel<<<(N_NODES + 255) / 256, 256, 0, stream>>>(deg_in, sum_log, s1, s2);
    {
        const int TOT = L_LAYERS * 256 * K13;
        wt_kernel<<<(TOT + 255) / 256, 256, 0, stream>>>(Ws, Wt);
        const int RT = L_LAYERS * R_REL * 256;
        cvt_kernel<<<(RT + 255) / 256, 256, 0, stream>>>(rel_embs, relh, RT);
        const int XT = N_NODES * 256;
        cvt_kernel<<<(XT + 255) / 256, 256, 0, stream>>>(x_in, xh0, XT);
    }
    hipMemcpyAsync(xb0, x_in, (size_t)N_NODES * 256 * 4, hipMemcpyDeviceToDevice, stream);

    float* xc = xb0; float* xn = xb1;
    _Float16* xhc = xh0; _Float16* xhn = xh1;
    for (int l = 0; l < L_LAYERS; l++) {
        agg_kernel<<<(N_NODES + 3) / 4, 256, 0, stream>>>(
            xc, xhc, relh + (size_t)l * R_REL * 256,
            offs, deg_in, csr_src, csr_et, feats);
        gemm_kernel<<<632, 256, 0, stream>>>(
            feats, xhc, Wt + (size_t)l * 256 * K13, s1, s2, hbuf);
        ln_kernel<<<(N_NODES + 3) / 4, 256, 0, stream>>>(
            hbuf, xc, bs + (size_t)l * 256, ln_s + (size_t)l * 256, ln_b + (size_t)l * 256, xn, xhn);
        float* t = xc; xc = xn; xn = t;
        _Float16* th = xhc; xhc = xhn; xhn = th;
    }
    score_kernel<<<(B_BATCH * K_BATCH + 3) / 4, 256, 0, stream>>>(xc, remb, batch, out);
}

// Round 11
// 471.041 us; speedup vs baseline: 1.2900x; 1.2900x over previous
//
#include <hip/hip_runtime.h>
#include <math.h>

typedef __attribute__((ext_vector_type(8))) _Float16 half8;
typedef __attribute__((ext_vector_type(4))) _Float16 half4;
typedef __attribute__((ext_vector_type(4))) float    floatx4;

#define N_NODES 10000
#define M_PAD   10112      // 79 * 128
#define MTILES  79
#define E_EDGES 160000
#define DIM     256
#define R_REL   237
#define L_LAYERS 6
#define B_BATCH 128
#define K_BATCH 33
#define K13     3328       // 13*256
#define WL_STRIDE 851968   // per-layer: 3*256*1024 + 256*256 halves
#define EPS_STD 1e-6f
#define EPS_LN  1e-5f

// async global->LDS, 16B per lane; LDS dest = wave-uniform base + lane*16
__device__ __forceinline__ void gload16(const void* g, void* lds) {
    __builtin_amdgcn_global_load_lds(
        (const __attribute__((address_space(1))) unsigned int*)g,
        (__attribute__((address_space(3))) unsigned int*)lds, 16, 0, 0);
}

// ---------------- CSR build ----------------
__global__ void hist_kernel(const int* __restrict__ dst, int* __restrict__ deg) {
    int e = blockIdx.x * blockDim.x + threadIdx.x;
    if (e < E_EDGES) atomicAdd(&deg[dst[e]], 1);
}

__global__ void scan_kernel(const int* __restrict__ deg_in, int* __restrict__ offs,
                            int* __restrict__ cursor, float* __restrict__ sum_log) {
    __shared__ int   part[1024];
    __shared__ float slog[1024];
    int t = threadIdx.x;
    const int CH = 10;
    int base = t * CH;
    int lsum = 0; float ls = 0.f;
    for (int j = 0; j < CH; j++) {
        int i = base + j;
        if (i < N_NODES) { int d = deg_in[i]; lsum += d; ls += logf((float)(d + 1)); }
    }
    part[t] = lsum; slog[t] = ls;
    __syncthreads();
    for (int off = 1; off < 1024; off <<= 1) {
        int v = (t >= off) ? part[t - off] : 0;
        __syncthreads();
        part[t] += v;
        __syncthreads();
    }
    int run = part[t] - lsum;
    for (int j = 0; j < CH; j++) {
        int i = base + j;
        if (i < N_NODES) { offs[i] = run; cursor[i] = run; run += deg_in[i]; }
    }
    __syncthreads();
    for (int off = 512; off > 0; off >>= 1) {
        if (t < off) slog[t] += slog[t + off];
        __syncthreads();
    }
    if (t == 0) sum_log[0] = slog[0];
}

__global__ void fill_kernel(const int* __restrict__ src, const int* __restrict__ dst,
                            const int* __restrict__ et, int* __restrict__ cursor,
                            int* __restrict__ csr_src, int* __restrict__ csr_et) {
    int e = blockIdx.x * blockDim.x + threadIdx.x;
    if (e < E_EDGES) {
        int d = dst[e];
        int p = atomicAdd(&cursor[d], 1);
        csr_src[p] = src[e];
        csr_et[p]  = et[e];
    }
}

__global__ void scales_kernel(const int* __restrict__ deg_in, const float* __restrict__ sum_log,
                              float* __restrict__ s1, float* __restrict__ s2) {
    int i = blockIdx.x * blockDim.x + threadIdx.x;
    if (i < N_NODES) {
        float mean = sum_log[0] * (1.0f / (float)N_NODES);
        float sc = logf((float)(deg_in[i] + 1)) / mean;
        s1[i] = sc;
        s2[i] = 1.0f / fmaxf(sc, 0.01f);
    }
}

// -------- W permute+transpose to fp16 (scales factored OUT of the GEMM) --------
// layout per layer: [s][n][k] s=0..2, k=t*256+d (korig = k*3+s), then [n][kx] for x (korig=3072+kx)
__global__ void wt_kernel(const float* __restrict__ Ws, _Float16* __restrict__ Wt) {
    int idx = blockIdx.x * 256 + threadIdx.x;
    const int TOT = L_LAYERS * WL_STRIDE;
    if (idx >= TOT) return;
    int l = idx / WL_STRIDE;
    int r = idx - l * WL_STRIDE;
    int korig, n;
    if (r < 786432) {                 // 3*256*1024
        int sidx = r / 262144;        // 256*1024
        int r2 = r - sidx * 262144;
        n = r2 >> 10;
        int k = r2 & 1023;
        korig = k * 3 + sidx;
    } else {
        int r2 = r - 786432;
        n = r2 >> 8;
        korig = 3072 + (r2 & 255);
    }
    Wt[idx] = (_Float16)Ws[(size_t)l * K13 * 256 + (size_t)korig * 256 + n];
}

// -------- fp32 -> fp16 converter --------
__global__ void cvt_kernel(const float* __restrict__ in, _Float16* __restrict__ outp, int n) {
    int i = blockIdx.x * 256 + threadIdx.x;
    if (i < n) outp[i] = (_Float16)in[i];
}

// ---- aggregation: one wave per node, 2 edges/iteration (lane halves), fp16 gather ----
__global__ void agg_kernel(const float* __restrict__ x, const _Float16* __restrict__ xh,
                           const _Float16* __restrict__ relh,
                           const int* __restrict__ offs, const int* __restrict__ deg_in,
                           const int* __restrict__ csr_src, const int* __restrict__ csr_et,
                           _Float16* __restrict__ feats) {
    int wid  = threadIdx.x >> 6;
    int lane = threadIdx.x & 63;
    int node = blockIdx.x * 4 + wid;
    if (node >= N_NODES) return;
    int half = lane >> 5;
    int sub  = lane & 31;
    int off = offs[node];
    int end = off + deg_in[node];
    const half8* xh8 = (const half8*)xh;
    const half8* rh8 = (const half8*)relh;

    float s_[8], q_[8], mx_[8], mn_[8];
    #pragma unroll
    for (int i = 0; i < 8; i++) { s_[i] = 0.f; q_[i] = 0.f; mx_[i] = -INFINITY; mn_[i] = INFINITY; }

    for (int base = off; base < end; base += 2) {
        int e = base + half;
        if (e < end) {
            int sN = csr_src[e];
            int et = csr_et[e];
            half8 xv = xh8[(size_t)sN * 32 + sub];
            half8 rv = rh8[(size_t)et * 32 + sub];
            #pragma unroll
            for (int i = 0; i < 8; i++) {
                float m = (float)xv[i] * (float)rv[i];
                s_[i] += m; q_[i] += m * m;
                mx_[i] = fmaxf(mx_[i], m);
                mn_[i] = fminf(mn_[i], m);
            }
        }
    }
    #pragma unroll
    for (int i = 0; i < 8; i++) {
        s_[i] += __shfl_xor(s_[i], 32);
        q_[i] += __shfl_xor(q_[i], 32);
        mx_[i] = fmaxf(mx_[i], __shfl_xor(mx_[i], 32));
        mn_[i] = fminf(mn_[i], __shfl_xor(mn_[i], 32));
    }
    const float4* xrow = (const float4*)(x + (size_t)node * 256);
    float4 xa = xrow[sub * 2], xb = xrow[sub * 2 + 1];
    float xs[8] = {xa.x, xa.y, xa.z, xa.w, xb.x, xb.y, xb.z, xb.w};
    #pragma unroll
    for (int i = 0; i < 8; i++) {
        s_[i] += xs[i]; q_[i] += xs[i] * xs[i];
        mx_[i] = fmaxf(mx_[i], xs[i]);
        mn_[i] = fminf(mn_[i], xs[i]);
    }
    float inv = 1.0f / (float)(end - off + 1);
    half8 hm, hx, hn, hs;
    #pragma unroll
    for (int i = 0; i < 8; i++) {
        float mean = s_[i] * inv;
        float sd = sqrtf(fmaxf(q_[i] * inv - mean * mean, EPS_STD));
        hm[i] = (_Float16)mean; hx[i] = (_Float16)mx_[i];
        hn[i] = (_Float16)mn_[i]; hs[i] = (_Float16)sd;
    }
    half8* fout = (half8*)(feats + (size_t)node * 1024);
    if (half == 0) {
        fout[0 * 32 + sub] = hm;
        fout[1 * 32 + sub] = hx;
    } else {
        fout[2 * 32 + sub] = hn;
        fout[3 * 32 + sub] = hs;
    }
}

// ---------------- fp16 MFMA GEMM: 4 unscaled panels (G0,G1,G2,Gx), pure gload_lds ----------------
// 128x128 tile, 2x2 waves (64x64 each), 3-buffer counted vmcnt(4).
// grid = 79m * 2nh * 4panels = 632 = 8*79 (exact XCD swizzle; ~10 m-strips + all panels per XCD)
__launch_bounds__(256, 3)
__global__ void gemm_kernel(const _Float16* __restrict__ feats, const _Float16* __restrict__ xh,
                            const _Float16* __restrict__ Wl, _Float16* __restrict__ hbuf) {
    __shared__ _Float16 sA[3][128 * 32];   // 24 KB
    __shared__ _Float16 sB[3][128 * 32];   // 24 KB

    // XCD swizzle: lin = xcd*79 + loc; lin -> (m, nh, sidx)
    int xcd = blockIdx.x & 7, loc = blockIdx.x >> 3;
    int lin = xcd * MTILES + loc;
    int sidx = lin & 3;
    int nh   = (lin >> 2) & 1;
    int m    = lin >> 3;
    const int i0 = m * 128;
    const int n0 = nh * 128;
    const int NS  = (sidx == 3) ? 8 : 32;   // K steps (wave-uniform)
    const int nit = (NS - 2) / 3;           // 2 or 10

    const int tid   = threadIdx.x;
    const int lane  = tid & 63;
    const int w     = tid >> 6;
    const int wr    = w >> 1;
    const int wc    = w & 1;
    const int row_l = lane & 15;
    const int kq    = lane >> 4;

    // reader LDS offsets (halves), XOR chunk swizzle: chunk' = chunk ^ ((row>>1)&3)
    int a_off[4], b_off[4];
    #pragma unroll
    for (int rf = 0; rf < 4; rf++) {
        int r = wr * 64 + rf * 16 + row_l;
        a_off[rf] = r * 32 + ((kq ^ ((r >> 1) & 3)) & 3) * 8;
    }
    #pragma unroll
    for (int cf = 0; cf < 4; cf++) {
        int n_ = wc * 64 + cf * 16 + row_l;
        b_off[cf] = n_ * 32 + ((kq ^ ((n_ >> 1) & 3)) & 3) * 8;
    }

    // staging sources (pre-swizzled global chunk, linear LDS dest); 2 gload16/wave each for A and B
    const char* a_src[2];
    const char* b_src[2];
    #pragma unroll
    for (int j = 0; j < 2; j++) {
        int rloc = j * 64 + w * 16 + (lane >> 2);
        int c = (lane & 3) ^ ((rloc >> 1) & 3);
        if (sidx < 3) {
            a_src[j] = (const char*)(feats + (size_t)(i0 + rloc) * 1024 + c * 8);
            b_src[j] = (const char*)(Wl + (size_t)sidx * 262144 + (size_t)(n0 + rloc) * 1024 + c * 8);
        } else {
            a_src[j] = (const char*)(xh + (size_t)(i0 + rloc) * 256 + c * 8);
            b_src[j] = (const char*)(Wl + 786432 + (size_t)(n0 + rloc) * 256 + c * 8);
        }
    }

    floatx4 acc[4][4];
    #pragma unroll
    for (int rf = 0; rf < 4; rf++)
        #pragma unroll
        for (int cf = 0; cf < 4; cf++)
            acc[rf][cf] = (floatx4){0.f, 0.f, 0.f, 0.f};

#define STAGE(BUF, S) do {                                                    \
    size_t koff_ = (size_t)(S) * 64; /* 32 halves * 2B */                     \
    gload16(a_src[0] + koff_, (char*)(&sA[BUF][0]) + (0 * 64 + w * 16) * 64); \
    gload16(a_src[1] + koff_, (char*)(&sA[BUF][0]) + (1 * 64 + w * 16) * 64); \
    gload16(b_src[0] + koff_, (char*)(&sB[BUF][0]) + (0 * 64 + w * 16) * 64); \
    gload16(b_src[1] + koff_, (char*)(&sB[BUF][0]) + (1 * 64 + w * 16) * 64); \
} while (0)

#define COMPUTE(CB) do {                                                      \
    half8 af[4], bf[4];                                                       \
    _Pragma("unroll")                                                         \
    for (int rf = 0; rf < 4; rf++) af[rf] = *(const half8*)(&sA[CB][a_off[rf]]); \
    _Pragma("unroll")                                                         \
    for (int cf = 0; cf < 4; cf++) bf[cf] = *(const half8*)(&sB[CB][b_off[cf]]); \
    _Pragma("unroll")                                                         \
    for (int rf = 0; rf < 4; rf++)                                            \
        _Pragma("unroll")                                                     \
        for (int cf = 0; cf < 4; cf++)                                        \
            acc[rf][cf] = __builtin_amdgcn_mfma_f32_16x16x32_f16(af[rf], bf[cf], acc[rf][cf], 0, 0, 0); \
} while (0)

// one step: stage S data ready (stage S+1's 4 ops may remain in flight), barrier,
// issue stage S+2, compute S
#define STEP(S, CB, NB) do {                                                  \
    asm volatile("s_waitcnt vmcnt(4)" ::: "memory");                          \
    __builtin_amdgcn_s_barrier();                                             \
    STAGE(NB, (S) + 2);                                                       \
    COMPUTE(CB);                                                              \
} while (0)

    // prologue: stages 0,1 in flight (4 vm-ops each per wave)
    STAGE(0, 0);
    STAGE(1, 1);

    // main loop: steps 0..NS-3 (NS ≡ 2 mod 3 for both 32 and 8)
    for (int it = 0; it < nit; ++it) {
        int s = it * 3;
        STEP(s + 0, 0, 2);
        STEP(s + 1, 1, 0);
        STEP(s + 2, 2, 1);
    }
    // step NS-2 (buf0): stage NS-1's 4 ops may remain
    asm volatile("s_waitcnt vmcnt(4)" ::: "memory");
    __builtin_amdgcn_s_barrier();
    COMPUTE(0);
    // step NS-1 (buf1): drain
    asm volatile("s_waitcnt vmcnt(0)" ::: "memory");
    __builtin_amdgcn_s_barrier();
    COMPUTE(1);

#undef STAGE
#undef COMPUTE
#undef STEP

    // C/D layout: col = lane&15, row = (lane>>4)*4 + j ; wave tile (wr*64, wc*64)
    _Float16* outb = hbuf + (size_t)sidx * M_PAD * 256;
    #pragma unroll
    for (int rf = 0; rf < 4; rf++) {
        #pragma unroll
        for (int j = 0; j < 4; j++) {
            int grow = i0 + wr * 64 + rf * 16 + kq * 4 + j;
            _Float16* orow = outb + (size_t)grow * 256 + n0 + wc * 64;
            #pragma unroll
            for (int cf = 0; cf < 4; cf++)
                orow[cf * 16 + row_l] = (_Float16)acc[rf][cf][j];
        }
    }
}

// ------- panel combine (G0 + s1*G1 + s2*G2 + Gx) + bias + LN + relu + residual -------
__global__ void ln_kernel(const _Float16* __restrict__ hbuf, const float* __restrict__ xin,
                          const float* __restrict__ s1a, const float* __restrict__ s2a,
                          const float* __restrict__ bvec, const float* __restrict__ gvec,
                          const float* __restrict__ evec, float* __restrict__ xout,
                          _Float16* __restrict__ xhout) {
    int wid = threadIdx.x >> 6, lane = threadIdx.x & 63;
    int row = blockIdx.x * 4 + wid;
    if (row >= N_NODES) return;
    const half4* p0 = (const half4*)(hbuf + (size_t)row * 256);
    const half4* p1 = (const half4*)(hbuf + (size_t)M_PAD * 256     + (size_t)row * 256);
    const half4* p2 = (const half4*)(hbuf + (size_t)M_PAD * 256 * 2 + (size_t)row * 256);
    const half4* p3 = (const half4*)(hbuf + (size_t)M_PAD * 256 * 3 + (size_t)row * 256);
    half4 h0 = p0[lane], h1 = p1[lane], h2 = p2[lane], h3 = p3[lane];
    float s1v = s1a[row], s2v = s2a[row];
    float4 bv = ((const float4*)bvec)[lane];
    float4 hv;
    hv.x = (float)h0.x + s1v * (float)h1.x + s2v * (float)h2.x + (float)h3.x + bv.x;
    hv.y = (float)h0.y + s1v * (float)h1.y + s2v * (float)h2.y + (float)h3.y + bv.y;
    hv.z = (float)h0.z + s1v * (float)h1.z + s2v * (float)h2.z + (float)h3.z + bv.z;
    hv.w = (float)h0.w + s1v * (float)h1.w + s2v * (float)h2.w + (float)h3.w + bv.w;
    float s = hv.x + hv.y + hv.z + hv.w;
    float qsq = hv.x*hv.x + hv.y*hv.y + hv.z*hv.z + hv.w*hv.w;
    #pragma unroll
    for (int off = 1; off < 64; off <<= 1) {
        s   += __shfl_xor(s, off);
        qsq += __shfl_xor(qsq, off);
    }
    float mu  = s * (1.0f / 256.0f);
    float var = qsq * (1.0f / 256.0f) - mu * mu;
    float rs  = rsqrtf(var + EPS_LN);
    float4 g = ((const float4*)gvec)[lane];
    float4 e = ((const float4*)evec)[lane];
    float4 xv = ((const float4*)(xin + (size_t)row * 256))[lane];
    float4 o;
    o.x = fmaxf((hv.x - mu) * rs * g.x + e.x, 0.f) + xv.x;
    o.y = fmaxf((hv.y - mu) * rs * g.y + e.y, 0.f) + xv.y;
    o.z = fmaxf((hv.z - mu) * rs * g.z + e.z, 0.f) + xv.z;
    o.w = fmaxf((hv.w - mu) * rs * g.w + e.w, 0.f) + xv.w;
    ((float4*)(xout + (size_t)row * 256))[lane] = o;
    half4 oh = { (_Float16)o.x, (_Float16)o.y, (_Float16)o.z, (_Float16)o.w };
    ((half4*)(xhout + (size_t)row * 256))[lane] = oh;
}

// ---------------- final scoring ----------------
__global__ void score_kernel(const float* __restrict__ x, const float* __restrict__ remb,
                             const int* __restrict__ batch, float* __restrict__ out) {
    int wid = threadIdx.x >> 6, lane = threadIdx.x & 63;
    int g = blockIdx.x * 4 + wid;
    if (g >= B_BATCH * K_BATCH) return;
    int si = batch[g * 3 + 0], ri = batch[g * 3 + 1], ti = batch[g * 3 + 2];
    const float4* xs = (const float4*)(x + (size_t)si * 256);
    const float4* xr = (const float4*)(remb + (size_t)ri * 256);
    const float4* xt = (const float4*)(x + (size_t)ti * 256);
    float4 a = xs[lane], r = xr[lane], t = xt[lane];
    float p = a.x*r.x*t.x + a.y*r.y*t.y + a.z*r.z*t.z + a.w*r.w*t.w;
    #pragma unroll
    for (int off = 1; off < 64; off <<= 1) p += __shfl_xor(p, off);
    if (lane == 0) out[g] = p;
}

extern "C" void kernel_launch(void* const* d_in, const int* in_sizes, int n_in,
                              void* d_out, int out_size, void* d_ws, size_t ws_size,
                              hipStream_t stream) {
    const float* x_in     = (const float*)d_in[0];
    const float* rel_embs = (const float*)d_in[1];
    const float* Ws       = (const float*)d_in[2];
    const float* bs       = (const float*)d_in[3];
    const float* ln_s     = (const float*)d_in[4];
    const float* ln_b     = (const float*)d_in[5];
    const float* remb     = (const float*)d_in[6];
    const int*   eidx     = (const int*)d_in[7];
    const int*   etype    = (const int*)d_in[8];
    const int*   batch    = (const int*)d_in[9];
    float* out = (float*)d_out;

    char* wp = (char*)d_ws;
    size_t o = 0;
    auto alloc = [&](size_t bytes) { void* p = wp + o; o += (bytes + 255) & ~255ull; return p; };
    int*      deg_in  = (int*)     alloc((size_t)N_NODES * 4);
    int*      offs    = (int*)     alloc((size_t)N_NODES * 4);
    int*      cursor  = (int*)     alloc((size_t)N_NODES * 4);
    float*    s1      = (float*)   alloc((size_t)M_PAD * 4);
    float*    s2      = (float*)   alloc((size_t)M_PAD * 4);
    float*    sum_log = (float*)   alloc(256);
    int*      csr_src = (int*)     alloc((size_t)E_EDGES * 4);
    int*      csr_et  = (int*)     alloc((size_t)E_EDGES * 4);
    _Float16* feats   = (_Float16*)alloc((size_t)M_PAD * 1024 * 2);           // 20.7 MB
    _Float16* Wt      = (_Float16*)alloc((size_t)L_LAYERS * WL_STRIDE * 2);   // 10.2 MB
    _Float16* hbuf    = (_Float16*)alloc((size_t)4 * M_PAD * 256 * 2);        // 20.7 MB
    float*    xb0     = (float*)   alloc((size_t)M_PAD * 256 * 4);
    float*    xb1     = (float*)   alloc((size_t)M_PAD * 256 * 4);
    _Float16* xh0     = (_Float16*)alloc((size_t)M_PAD * 256 * 2);
    _Float16* xh1     = (_Float16*)alloc((size_t)M_PAD * 256 * 2);
    _Float16* relh    = (_Float16*)alloc((size_t)L_LAYERS * R_REL * 256 * 2); // 0.73 MB

    const int* src  = eidx;
    const int* dstp = eidx + E_EDGES;

    hipMemsetAsync(deg_in, 0, (size_t)N_NODES * 4, stream);
    hist_kernel<<<(E_EDGES + 255) / 256, 256, 0, stream>>>(dstp, deg_in);
    scan_kernel<<<1, 1024, 0, stream>>>(deg_in, offs, cursor, sum_log);
    fill_kernel<<<(E_EDGES + 255) / 256, 256, 0, stream>>>(src, dstp, etype, cursor, csr_src, csr_et);
    scales_kernel<<<(N_NODES + 255) / 256, 256, 0, stream>>>(deg_in, sum_log, s1, s2);
    {
        const int TOT = L_LAYERS * WL_STRIDE;
        wt_kernel<<<(TOT + 255) / 256, 256, 0, stream>>>(Ws, Wt);
        const int RT = L_LAYERS * R_REL * 256;
        cvt_kernel<<<(RT + 255) / 256, 256, 0, stream>>>(rel_embs, relh, RT);
        const int XT = N_NODES * 256;
        cvt_kernel<<<(XT + 255) / 256, 256, 0, stream>>>(x_in, xh0, XT);
    }
    hipMemcpyAsync(xb0, x_in, (size_t)N_NODES * 256 * 4, hipMemcpyDeviceToDevice, stream);

    float* xc = xb0; float* xn = xb1;
    _Float16* xhc = xh0; _Float16* xhn = xh1;
    for (int l = 0; l < L_LAYERS; l++) {
        agg_kernel<<<(N_NODES + 3) / 4, 256, 0, stream>>>(
            xc, xhc, relh + (size_t)l * R_REL * 256,
            offs, deg_in, csr_src, csr_et, feats);
        gemm_kernel<<<632, 256, 0, stream>>>(
            feats, xhc, Wt + (size_t)l * WL_STRIDE, hbuf);
        ln_kernel<<<(N_NODES + 3) / 4, 256, 0, stream>>>(
            hbuf, xc, s1, s2, bs + (size_t)l * 256, ln_s + (size_t)l * 256,
            ln_b + (size_t)l * 256, xn, xhn);
        float* t = xc; xc = xn; xn = t;
        _Float16* th = xhc; xhc = xhn; xhn = th;
    }
    score_kernel<<<(B_BATCH * K_BATCH + 3) / 4, 256, 0, stream>>>(xc, remb, batch, out);
}